// Round 1
// 317.713 us; speedup vs baseline: 1.0970x; 1.0970x over previous
//
#include <hip/hip_runtime.h>
#include <cstdint>
#include <cstddef>

#define N_NODES 50000
#define N_EDGES 300000
#define DIM     256
#define KTOT    768   // concatenated K: [agg*norm | h | prev_h]
#define N_RELS  500

#define SCAN_BLK  256
#define SCAN_NBLK ((N_NODES + SCAN_BLK - 1) / SCAN_BLK)   // 196

typedef unsigned short u16;
typedef __attribute__((ext_vector_type(8))) short short8v;   // 8 bf16 = 4 VGPRs (MFMA A/B frag)
typedef __attribute__((ext_vector_type(4))) float float4v;   // MFMA C/D frag

static __device__ __forceinline__ u16 f2bf(float f) {
    union { float f; unsigned u; } v; v.f = f;
    unsigned u = v.u;
    unsigned r = u + 0x7FFFu + ((u >> 16) & 1u);  // RNE
    return (u16)(r >> 16);
}
static __device__ __forceinline__ float bf2f(u16 b) {
    union { unsigned u; float f; } v; v.u = ((unsigned)b) << 16; return v.f;
}

// async global->LDS, 16B per lane, LDS dest = wave-uniform base + lane*16 (linear)
static __device__ __forceinline__ void gld16(const void* g, u16* l) {
    __builtin_amdgcn_global_load_lds(
        (const __attribute__((address_space(1))) unsigned int*)g,
        (__attribute__((address_space(3))) unsigned int*)l,
        16, 0, 0);
}

// ---------------- K1: h -> Xcat[:,256:512] (bf16), emb -> embb (bf16) ----------------
__global__ void conv_kernel(const float* __restrict__ h, const float* __restrict__ emb,
                            u16* __restrict__ Xcat, u16* __restrict__ embb) {
    int i = blockIdx.x * blockDim.x + threadIdx.x;
    int e0 = i * 8;
    if (e0 >= (N_NODES + N_RELS) * DIM) return;
    const float* src; u16* dst;
    if (e0 < N_NODES * DIM) {
        int n = e0 >> 8, c = e0 & 255;
        src = h + e0;
        dst = Xcat + (size_t)n * 512 + 256 + c;   // h-slice of Xcat
    } else {
        int off = e0 - N_NODES * DIM;
        src = emb + off; dst = embb + off;
    }
    float4 a = *(const float4*)(src);
    float4 b = *(const float4*)(src + 4);
    u16 o[8] = { f2bf(a.x), f2bf(a.y), f2bf(a.z), f2bf(a.w),
                 f2bf(b.x), f2bf(b.y), f2bf(b.z), f2bf(b.w) };
    *(uint4*)dst = *(const uint4*)o;
}

// ---------------- K2: build Wt[d][k] = Wseg[k%256][d] (bf16, B^T layout) ----------------
__global__ void wt_kernel(const float* __restrict__ Wn, const float* __restrict__ Wl,
                          const float* __restrict__ Wsc, u16* __restrict__ Wt) {
    int k = blockIdx.x;    // 0..767
    int d = threadIdx.x;   // 0..255
    const float* W = (k < 256) ? Wn : ((k < 512) ? Wl : Wsc);
    int kk = k & 255;
    Wt[(size_t)d * KTOT + k] = f2bf(W[kk * DIM + d]);
}

// ---------------- K3: in-degree histogram ----------------
__global__ void hist_kernel(const int* __restrict__ dstv, int* __restrict__ deg) {
    int e = blockIdx.x * 256 + threadIdx.x;
    if (e < N_EDGES) atomicAdd(&deg[dstv[e]], 1);
}

// ---------------- K4a: per-block scan of deg ----------------
__global__ void scanA_kernel(const int* __restrict__ deg, int* __restrict__ excl_local,
                             int* __restrict__ block_sum) {
    __shared__ int sdata[SCAN_BLK];
    int t = threadIdx.x, i = blockIdx.x * SCAN_BLK + t;
    int v = (i < N_NODES) ? deg[i] : 0;
    sdata[t] = v;
    __syncthreads();
    for (int off = 1; off < SCAN_BLK; off <<= 1) {
        int u = (t >= off) ? sdata[t - off] : 0;
        __syncthreads();
        sdata[t] += u;
        __syncthreads();
    }
    if (i < N_NODES) excl_local[i] = sdata[t] - v;
    if (t == SCAN_BLK - 1) block_sum[blockIdx.x] = sdata[t];
}

// ---------------- K4b: scan 196 block sums (1 block) ----------------
__global__ void scanB_kernel(const int* __restrict__ block_sum, int* __restrict__ block_base,
                             int* __restrict__ offsets) {
    __shared__ int sdata[SCAN_NBLK];
    int t = threadIdx.x;
    int v = (t < SCAN_NBLK) ? block_sum[t] : 0;
    if (t < SCAN_NBLK) sdata[t] = v;
    __syncthreads();
    for (int off = 1; off < SCAN_NBLK; off <<= 1) {
        int u = (t >= off && t < SCAN_NBLK) ? sdata[t - off] : 0;
        __syncthreads();
        if (t < SCAN_NBLK) sdata[t] += u;
        __syncthreads();
    }
    if (t < SCAN_NBLK) block_base[t] = sdata[t] - v;
    if (t == SCAN_NBLK - 1) offsets[N_NODES] = sdata[t];
}

// ---------------- K4c: combine -> offsets, cursor ----------------
__global__ void scanC_kernel(const int* __restrict__ excl_local, const int* __restrict__ block_base,
                             int* __restrict__ offsets, int* __restrict__ cursor) {
    int i = blockIdx.x * SCAN_BLK + threadIdx.x;
    if (i < N_NODES) {
        int e = block_base[blockIdx.x] + excl_local[i];
        offsets[i] = e; cursor[i] = e;
    }
}

// ---------------- K5: scatter edges into CSR slots (packed src*500+et) ----------------
__global__ void scatter_kernel(const int* __restrict__ src, const int* __restrict__ dstv,
                               const int* __restrict__ et, int* __restrict__ cursor,
                               unsigned* __restrict__ esee) {
    int e = blockIdx.x * 256 + threadIdx.x;
    if (e >= N_EDGES) return;
    int d = dstv[e];
    int pos = atomicAdd(&cursor[d], 1);
    esee[pos] = (unsigned)src[e] * N_RELS + (unsigned)et[e];
}

// ---------------- K6: wave-per-node gather-reduce -> Xcat[:,0:256] ----------------
// 2-edge unroll for memory-level parallelism (latency-bound gather).
__global__ void agg_kernel(u16* __restrict__ Xcat, const u16* __restrict__ embb,
                           const float* __restrict__ norm, const int* __restrict__ offsets,
                           const unsigned* __restrict__ esee,
                           int* __restrict__ wl_count, int* __restrict__ wl) {
    int wave = (blockIdx.x * 256 + threadIdx.x) >> 6;
    int lane = threadIdx.x & 63;
    if (wave >= N_NODES) return;
    int n = wave;
    int s0 = offsets[n], s1 = offsets[n + 1];
    int c4 = lane * 4;
    float4 acc = make_float4(0.f, 0.f, 0.f, 0.f);
    int e = s0;
    for (; e + 1 < s1; e += 2) {
        unsigned v0 = esee[e], v1 = esee[e + 1];
        unsigned sa = v0 / N_RELS, ta = v0 - sa * N_RELS;
        unsigned sb = v1 / N_RELS, tb = v1 - sb * N_RELS;
        ushort4 ha = *(const ushort4*)(Xcat + (size_t)sa * 512 + 256 + c4);
        ushort4 ea = *(const ushort4*)(embb + (size_t)ta * DIM + c4);
        ushort4 hb = *(const ushort4*)(Xcat + (size_t)sb * 512 + 256 + c4);
        ushort4 eb = *(const ushort4*)(embb + (size_t)tb * DIM + c4);
        acc.x += bf2f(ha.x) + bf2f(ea.x) + bf2f(hb.x) + bf2f(eb.x);
        acc.y += bf2f(ha.y) + bf2f(ea.y) + bf2f(hb.y) + bf2f(eb.y);
        acc.z += bf2f(ha.z) + bf2f(ea.z) + bf2f(hb.z) + bf2f(eb.z);
        acc.w += bf2f(ha.w) + bf2f(ea.w) + bf2f(hb.w) + bf2f(eb.w);
    }
    if (e < s1) {
        unsigned v = esee[e];
        unsigned s = v / N_RELS;
        unsigned t = v - s * N_RELS;
        ushort4 hv = *(const ushort4*)(Xcat + (size_t)s * 512 + 256 + c4);
        ushort4 ev = *(const ushort4*)(embb + (size_t)t * DIM + c4);
        acc.x += bf2f(hv.x) + bf2f(ev.x);
        acc.y += bf2f(hv.y) + bf2f(ev.y);
        acc.z += bf2f(hv.z) + bf2f(ev.z);
        acc.w += bf2f(hv.w) + bf2f(ev.w);
    }
    float nr = norm[n];
    u16 o[4] = { f2bf(acc.x * nr), f2bf(acc.y * nr), f2bf(acc.z * nr), f2bf(acc.w * nr) };
    *(ushort4*)(Xcat + (size_t)n * 512 + c4) = *(const ushort4*)o;
    if (lane == 0 && s1 == s0) { int idx = atomicAdd(wl_count, 1); wl[idx] = n; }
}

// ---------------- K7: fused MFMA GEMM, 2-phase double-buffered pipeline ----------------
// Block: 256 thr = 4 waves. Tile: 64 nodes x 256 cols (wave w: cols [w*64,+64)). BK=64.
// Staging: global_load_lds width=16 into LINEAR LDS, source pre-swizzled by
// chunk ^= (row&7)  (<=> byte ^ ((row&7)<<4)), reads apply the same XOR (rule #21).
// kt 0..7 A from Xcat (bf16); kt 8..11 A = prev_h fp32 staged issue-early/write-late (T14).
// LDS: A 2x8KB @u16[0 / 4096], B 2x32KB @u16[8192 / 24576] = 80KB -> 2 blocks/CU.
__launch_bounds__(256, 2)
__global__ void gemm_kernel(const u16* __restrict__ Xcat, const u16* __restrict__ Wt,
                            const float* __restrict__ prev_h, const float* __restrict__ bias,
                            float* __restrict__ out) {
    __shared__ __align__(16) u16 lds[40960];   // 81920 B
    int tid  = threadIdx.x;
    int wave = tid >> 6, lane = tid & 63, q = lane >> 4, m16 = lane & 15;
    int wn = wave * 64;
    int m0 = blockIdx.x * 64;
    int lr = lane >> 3, lc8 = lane & 7;        // staging: row-in-chunk / 16B-chunk-in-row
    int scol = (lc8 ^ lr) << 3;                // pre-swizzled source col (u16 units)

    // staging source pointers (A: 2 chunks of 8 rows; B: 8 chunks of 8 rows)
    int ar0 = wave * 16 + lr, ar1 = ar0 + 8;
    int ga0 = (m0 + ar0 < N_NODES) ? (m0 + ar0) : (N_NODES - 1);
    int ga1 = (m0 + ar1 < N_NODES) ? (m0 + ar1) : (N_NODES - 1);
    const u16*   sA0 = Xcat   + (size_t)ga0 * 512 + scol;
    const u16*   sA1 = Xcat   + (size_t)ga1 * 512 + scol;
    const float* pP0 = prev_h + (size_t)ga0 * 256 + scol;
    const float* pP1 = prev_h + (size_t)ga1 * 256 + scol;
    const u16*   sB  = Wt + (size_t)(wave * 64 + lr) * KTOT + scol;  // + j*8*KTOT + kt*64
    // LDS dest bases (wave-uniform, u16 units)
    int ldsA_w = wave * 16 * 64;          // + buf*4096 (+512 for j=1)
    int ldsB_w = 8192 + wave * 64 * 64;   // + buf*16384 (+j*512)

    float4v acc1[4][4], acc2[4][4];
#pragma unroll
    for (int i = 0; i < 4; i++)
#pragma unroll
        for (int j = 0; j < 4; j++) { acc1[i][j] = (float4v)0.f; acc2[i][j] = (float4v)0.f; }

    // ---- prologue: stage kt=0 into buf 0 ----
#pragma unroll
    for (int j = 0; j < 8; j++)
        gld16(sB + (size_t)j * 8 * KTOT, &lds[ldsB_w + j * 512]);
    gld16(sA0, &lds[ldsA_w]);
    gld16(sA1, &lds[ldsA_w + 512]);
    __syncthreads();

    int sw = (m16 & 7) << 3;   // read-side swizzle (u16 units)

#pragma unroll
    for (int kt = 0; kt < 12; kt++) {
        int buf = kt & 1, nbuf = buf ^ 1;
        float pf0[8], pf1[8];
        // ---- issue next-tile staging (loads stay in flight under compute) ----
        if (kt < 11) {
            int kn = kt + 1;
#pragma unroll
            for (int j = 0; j < 8; j++)
                gld16(sB + (size_t)j * 8 * KTOT + kn * 64,
                      &lds[ldsB_w + nbuf * 16384 + j * 512]);
            if (kn < 8) {
                gld16(sA0 + kn * 64, &lds[ldsA_w + nbuf * 4096]);
                gld16(sA1 + kn * 64, &lds[ldsA_w + nbuf * 4096 + 512]);
            } else {
                const float* p0 = pP0 + (kn - 8) * 64;
                const float* p1 = pP1 + (kn - 8) * 64;
                float4 x0 = *(const float4*)p0, y0 = *(const float4*)(p0 + 4);
                float4 x1 = *(const float4*)p1, y1 = *(const float4*)(p1 + 4);
                pf0[0] = x0.x; pf0[1] = x0.y; pf0[2] = x0.z; pf0[3] = x0.w;
                pf0[4] = y0.x; pf0[5] = y0.y; pf0[6] = y0.z; pf0[7] = y0.w;
                pf1[0] = x1.x; pf1[1] = x1.y; pf1[2] = x1.z; pf1[3] = x1.w;
                pf1[4] = y1.x; pf1[5] = y1.y; pf1[6] = y1.z; pf1[7] = y1.w;
            }
        }
        // ---- compute current tile ----
#pragma unroll
        for (int kk = 0; kk < 2; kk++) {
            int ck = (kk * 32 + q * 8) ^ sw;
            short8v af[4], bfr[4];
#pragma unroll
            for (int mi = 0; mi < 4; mi++)
                af[mi] = *(const short8v*)(&lds[buf * 4096 + (mi * 16 + m16) * 64 + ck]);
#pragma unroll
            for (int ni = 0; ni < 4; ni++)
                bfr[ni] = *(const short8v*)(&lds[8192 + buf * 16384 + (wn + ni * 16 + m16) * 64 + ck]);
            if (kt < 8) {
#pragma unroll
                for (int mi = 0; mi < 4; mi++)
#pragma unroll
                    for (int ni = 0; ni < 4; ni++)
                        acc1[mi][ni] = __builtin_amdgcn_mfma_f32_16x16x32_bf16(
                            af[mi], bfr[ni], acc1[mi][ni], 0, 0, 0);
            } else {
#pragma unroll
                for (int mi = 0; mi < 4; mi++)
#pragma unroll
                    for (int ni = 0; ni < 4; ni++)
                        acc2[mi][ni] = __builtin_amdgcn_mfma_f32_16x16x32_bf16(
                            af[mi], bfr[ni], acc2[mi][ni], 0, 0, 0);
            }
        }
        // ---- late write of reg-staged prev_h (same linear-dest/swizzled-src mapping) ----
        if (kt < 11 && kt + 1 >= 8) {
            u16 o0[8] = { f2bf(pf0[0]), f2bf(pf0[1]), f2bf(pf0[2]), f2bf(pf0[3]),
                          f2bf(pf0[4]), f2bf(pf0[5]), f2bf(pf0[6]), f2bf(pf0[7]) };
            u16 o1[8] = { f2bf(pf1[0]), f2bf(pf1[1]), f2bf(pf1[2]), f2bf(pf1[3]),
                          f2bf(pf1[4]), f2bf(pf1[5]), f2bf(pf1[6]), f2bf(pf1[7]) };
            *(uint4*)(&lds[nbuf * 4096 + ar0 * 64 + lc8 * 8]) = *(const uint4*)o0;
            *(uint4*)(&lds[nbuf * 4096 + ar1 * 64 + lc8 * 8]) = *(const uint4*)o1;
        }
        __syncthreads();
    }

    // epilogue: C/D layout col=lane&15, row=q*4+reg  [measured m89]
#pragma unroll
    for (int mi = 0; mi < 4; mi++) {
#pragma unroll
        for (int ni = 0; ni < 4; ni++) {
            int d = wn + ni * 16 + m16;
            float b = bias[d];
#pragma unroll
            for (int r = 0; r < 4; r++) {
                int node = m0 + mi * 16 + q * 4 + r;
                if (node < N_NODES) {
                    float S  = acc2[mi][ni][r] + b;
                    float sg = 1.f / (1.f + __expf(-S));
                    float ph = prev_h[(size_t)node * DIM + d];
                    float v  = sg * acc1[mi][ni][r] + (1.f - sg) * ph;
                    out[(size_t)node * DIM + d] = fmaxf(v, 0.f);
                }
            }
        }
    }
}

// ---------------- K8: fixup for in_deg==0 nodes (evolve_loop_weight path, exact fp32) --------
__global__ void fixup_kernel(const float* __restrict__ h, const float* __restrict__ prev_h,
                             const float* __restrict__ We, const float* __restrict__ Wsc,
                             const float* __restrict__ bias, const int* __restrict__ wl_count,
                             const int* __restrict__ wl, float* __restrict__ out) {
    __shared__ float ph[DIM], hh[DIM];
    int d = threadIdx.x;
    int cnt = *wl_count;
    for (int i = blockIdx.x; i < cnt; i += gridDim.x) {
        int n = wl[i];
        ph[d] = prev_h[(size_t)n * DIM + d];
        hh[d] = h[(size_t)n * DIM + d];
        __syncthreads();
        float s = 0.f, l = 0.f;
        for (int k = 0; k < DIM; k++) {
            s += ph[k] * Wsc[k * DIM + d];
            l += hh[k] * We[k * DIM + d];
        }
        float sg = 1.f / (1.f + __expf(-(s + bias[d])));
        float v = sg * l + (1.f - sg) * ph[d];
        out[(size_t)n * DIM + d] = fmaxf(v, 0.f);
        __syncthreads();
    }
}

extern "C" void kernel_launch(void* const* d_in, const int* in_sizes, int n_in,
                              void* d_out, int out_size, void* d_ws, size_t ws_size,
                              hipStream_t stream) {
    const float* h      = (const float*)d_in[0];
    const float* prev_h = (const float*)d_in[1];
    const float* emb    = (const float*)d_in[2];
    const float* norm   = (const float*)d_in[3];
    const float* Wn     = (const float*)d_in[4];
    const float* Wl     = (const float*)d_in[5];
    const float* We     = (const float*)d_in[6];
    const float* Wsc    = (const float*)d_in[7];
    const float* bias   = (const float*)d_in[8];
    const int*   src    = (const int*)d_in[9];
    const int*   dstv   = (const int*)d_in[10];
    const int*   et     = (const int*)d_in[11];
    float* out = (float*)d_out;

    char* ws = (char*)d_ws;
    size_t off = 0;
    auto alloc = [&](size_t bytes) -> char* {
        char* p = ws + off; off += (bytes + 255) & ~(size_t)255; return p;
    };
    u16* Xcat    = (u16*)alloc((size_t)N_NODES * 512 * 2);   // [agg | h] bf16, 512 cols
    u16* embb    = (u16*)alloc((size_t)N_RELS * DIM * 2);
    u16* Wt      = (u16*)alloc((size_t)DIM * KTOT * 2);
    int* deg     = (int*)alloc((size_t)N_NODES * 4);
    int* wlcnt   = (int*)alloc(16);
    int* wl      = (int*)alloc((size_t)N_NODES * 4);
    int* offsets = (int*)alloc((size_t)(N_NODES + 1) * 4);
    int* cursor  = (int*)alloc((size_t)N_NODES * 4);
    unsigned* esee = (unsigned*)alloc((size_t)N_EDGES * 4);
    int* excl    = (int*)alloc((size_t)N_NODES * 4);
    int* bsum    = (int*)alloc((size_t)SCAN_NBLK * 4);
    int* bbase   = (int*)alloc((size_t)SCAN_NBLK * 4);

    hipMemsetAsync(deg, 0, (size_t)N_NODES * 4, stream);
    hipMemsetAsync(wlcnt, 0, 4, stream);

    conv_kernel<<<((N_NODES + N_RELS) * DIM / 8 + 255) / 256, 256, 0, stream>>>(h, emb, Xcat, embb);
    wt_kernel<<<KTOT, 256, 0, stream>>>(Wn, Wl, Wsc, Wt);
    hist_kernel<<<(N_EDGES + 255) / 256, 256, 0, stream>>>(dstv, deg);
    scanA_kernel<<<SCAN_NBLK, SCAN_BLK, 0, stream>>>(deg, excl, bsum);
    scanB_kernel<<<1, SCAN_BLK, 0, stream>>>(bsum, bbase, offsets);
    scanC_kernel<<<SCAN_NBLK, SCAN_BLK, 0, stream>>>(excl, bbase, offsets, cursor);
    scatter_kernel<<<(N_EDGES + 255) / 256, 256, 0, stream>>>(src, dstv, et, cursor, esee);
    agg_kernel<<<(N_NODES + 3) / 4, 256, 0, stream>>>(Xcat, embb, norm, offsets, esee, wlcnt, wl);
    gemm_kernel<<<(N_NODES + 63) / 64, 256, 0, stream>>>(Xcat, Wt, prev_h, bias, out);
    fixup_kernel<<<256, 256, 0, stream>>>(h, prev_h, We, Wsc, bias, wlcnt, wl, out);
}